// Round 6
// baseline (140.110 us; speedup 1.0000x reference)
//
#include <hip/hip_runtime.h>
#include <hip/hip_bf16.h>
#include <hip/hip_fp16.h>

// ModulatedDeformConv2d forward: f16 NHWC x, XCD-swizzled,
// producer/consumer wave-specialized fused sample+MFMA.
// R15 = R14 with the GATHER_ISSUE addressing bug fixed: second 8-channel
// half of each thread's 16-channel quarter is at +16 BYTES (8 ch x 2B),
// not +64. R14's +64 read the wrong channels -> absmax 1.42 FAIL.
// Pipeline: producers issue tap k+1's 8 gathers BEFORE blending tap k
// (double-buffered gather registers, vmcnt(8) steady state); consumers
// prefetch tap k+1's A-fragments before the MFMA cluster.
// x[8,64,128,128] f32, offset[8,18,128,128], mask[8,9,128,128],
// weight[64,64,3,3], bias[64]; out[8,64,128,128] f32.

constexpr int B    = 8;
constexpr int C    = 64;
constexpr int H    = 128;
constexpr int W    = 128;
constexpr int COUT = 64;
constexpr int K2   = 9;
constexpr int HW   = H * W;
constexpr int TPX  = 64;   // pixels per tile

typedef __attribute__((ext_vector_type(8))) short    short8;
typedef __attribute__((ext_vector_type(8))) _Float16 f16x8;
typedef __attribute__((ext_vector_type(4))) float    f32x4;

// LDS tile row: 64 ch padded to 72 halves (144 B).
constexpr int LDSS = 72;

// Raw workgroup barrier: drain LDS ops only (no vmcnt(0) drain).
#define LDS_BARRIER() asm volatile("s_waitcnt lgkmcnt(0)\n\ts_barrier" ::: "memory")

// ---------- x: NCHW f32 -> NHWC f16 ----------
__global__ __launch_bounds__(256) void transpose_x_kernel(
    const float* __restrict__ x, short* __restrict__ xt) {
    __shared__ float tbuf[64][65];
    const int blk  = blockIdx.x;          // B * (HW/64) = 2048
    const int b    = blk >> 8;
    const int hwb  = (blk & 255) * 64;
    const int lane = threadIdx.x & 63;
    const int grp  = threadIdx.x >> 6;    // 0..3
    const float* xb = x + (size_t)b * C * HW;
#pragma unroll
    for (int r = 0; r < 16; ++r) {
        const int c = grp * 16 + r;
        tbuf[c][lane] = xb[c * HW + hwb + lane];   // coalesced along hw
    }
    __syncthreads();
    short* xo = xt + (size_t)b * HW * C;
#pragma unroll
    for (int r = 0; r < 16; ++r) {
        const int hw_l = grp * 16 + r;
        union { __half h; short s; } u;
        u.h = __float2half(tbuf[lane][hw_l]);
        xo[(size_t)(hwb + hw_l) * C + lane] = u.s;  // coalesced along c
    }
}

// ---------- weight[o][c][3][3] f32 -> A-fragment-ordered f16 ----------
// wfrag[(k*8 + kk*4 + mt)*64 + lane][j] = f16( w[m][c][k] )
//   m = mt*16 + (lane&15), q = lane>>4, c = kk*32 + q*8 + j
__global__ __launch_bounds__(256) void pack_w_kernel(
    const float* __restrict__ w, short* __restrict__ wfrag) {
    int id = blockIdx.x * blockDim.x + threadIdx.x;
    if (id >= COUT * C * K2) return;
    const int j    = id & 7;
    const int lane = (id >> 3) & 63;
    const int mt   = (id >> 9) & 3;
    const int kk   = (id >> 11) & 1;
    const int k    = id >> 12;
    const int m    = mt * 16 + (lane & 15);
    const int q    = lane >> 4;
    const int c    = kk * 32 + q * 8 + j;
    union { __half h; short s; } u;
    u.h = __float2half(w[(m * C + c) * K2 + k]);
    wfrag[id] = u.s;
}

// issue all 8 corner gathers of one tap into gdst[0..7]
// [0..3] = corners (y0x0, y0x1, y1x0, y1x1) of 8-channel half 0,
// [4..7] = same corners of 8-channel half 1 (+16 BYTES = 8 ch x 2 B).
#define GATHER_ISSUE(gdst, bv)                                   \
    gdst[0] = *(const short8*)(xb + (bv).x);                     \
    gdst[1] = *(const short8*)(xb + (bv).y);                     \
    gdst[2] = *(const short8*)(xb + (bv).z);                     \
    gdst[3] = *(const short8*)(xb + (bv).w);                     \
    gdst[4] = *(const short8*)(xb + (bv).x + 16);                \
    gdst[5] = *(const short8*)(xb + (bv).y + 16);                \
    gdst[6] = *(const short8*)(xb + (bv).z + 16);                \
    gdst[7] = *(const short8*)(xb + (bv).w + 16);

// ---------- producer/consumer fused kernel ----------
// grid 2048: b = wg&7 (XCD round-robin -> per-XCD-L2-resident f16 x),
// t = wg>>3 -> (ho, 64-px half-row). 512 threads = 8 waves.
__global__ __launch_bounds__(512, 4) void mdcn_pc_kernel(
    const short* __restrict__ xt,      // [B][H][W][C] f16
    const float* __restrict__ offset,
    const float* __restrict__ mask,
    const short* __restrict__ wfrag,
    const float* __restrict__ bias,
    float* __restrict__ out) {

    __shared__ short smem[2][TPX * LDSS];    // 2 x 9216 B
    __shared__ int4  pidx[K2 * TPX];         // 9216 B: 4 corner byte-offsets
    __shared__ uint4 pwts[K2 * TPX];         // 9216 B: 4 blend wts as (h,h) half2

    const int wg   = blockIdx.x;
    const int b    = wg & 7;
    const int t    = wg >> 3;                // 0..255
    const int ho   = t >> 1;
    const int px0  = (t & 1) * TPX;

    const int tid  = threadIdx.x;
    const int wave = tid >> 6;

    // ---- precompute ALL taps' sampling params (one thread per (tap,px)) ----
    for (int f = tid; f < K2 * TPX; f += 512) {
        const int k = f >> 6;                // tap
        const int i = f & 63;                // tile-local pixel
        const int wo = px0 + i;
        const int ky = k / 3, kx = k % 3;
        const float dx = offset[(((size_t)b * 2 * K2 + 2 * k    ) * H + ho) * W + wo];
        const float dy = offset[(((size_t)b * 2 * K2 + 2 * k + 1) * H + ho) * W + wo];
        const float mm = mask  [(((size_t)b * K2     + k        ) * H + ho) * W + wo];
        const float py = (float)(ho - 1 + ky) + dy;
        const float px = (float)(wo - 1 + kx) + dx;
        const float y0f = floorf(py), x0f = floorf(px);
        const float wy1 = py - y0f,   wx1 = px - x0f;
        const float wy0 = 1.0f - wy1, wx0 = 1.0f - wx1;
        const int iy0 = (int)y0f, ix0 = (int)x0f;
        const int iy1 = iy0 + 1,  ix1 = ix0 + 1;
        const bool vy0 = (iy0 >= 0) & (iy0 < H);
        const bool vy1 = (iy1 >= 0) & (iy1 < H);
        const bool vx0 = (ix0 >= 0) & (ix0 < W);
        const bool vx1 = (ix1 >= 0) & (ix1 < W);
        const float w00 = (vy0 & vx0) ? wy0 * wx0 * mm : 0.0f;
        const float w01 = (vy0 & vx1) ? wy0 * wx1 * mm : 0.0f;
        const float w10 = (vy1 & vx0) ? wy1 * wx0 * mm : 0.0f;
        const float w11 = (vy1 & vx1) ? wy1 * wx1 * mm : 0.0f;
        union { __half2 h2; unsigned u; } c0, c1, c2, c3;
        c0.h2 = __floats2half2_rn(w00, w00);
        c1.h2 = __floats2half2_rn(w01, w01);
        c2.h2 = __floats2half2_rn(w10, w10);
        c3.h2 = __floats2half2_rn(w11, w11);
        uint4 wv;
        wv.x = c0.u; wv.y = c1.u; wv.z = c2.u; wv.w = c3.u;
        const int cy0 = min(max(iy0, 0), H - 1);
        const int cy1 = min(max(iy1, 0), H - 1);
        const int cx0 = min(max(ix0, 0), W - 1);
        const int cx1 = min(max(ix1, 0), W - 1);
        int4 bv;                              // byte offsets into xb
        bv.x = (cy0 * W + cx0) * (C * 2);
        bv.y = (cy0 * W + cx1) * (C * 2);
        bv.z = (cy1 * W + cx0) * (C * 2);
        bv.w = (cy1 * W + cx1) * (C * 2);
        pidx[f] = bv;
        pwts[f] = wv;
    }
    __syncthreads();                         // init barrier (full fence, once)

    if (wave < 4) {
        // ================= PRODUCER: sample -> LDS (pipelined) =============
        const int spx = tid >> 2;            // 0..63 pixel in tile
        const int cq  = (tid & 3) * 16;      // 16-channel quarter
        const char* xb =
            (const char*)(xt + (size_t)b * HW * C) + cq * 2;

        short8 ga[8], gb[8];                 // double-buffered gather data
        {
            const int4 bi0 = pidx[spx];      // tap 0 corner offsets
            GATHER_ISSUE(ga, bi0);           // tap 0 in flight
        }
#pragma unroll
        for (int k = 0; k < K2; ++k) {
            auto& gc = (k & 1) ? gb : ga;    // current tap's data (in flight)
            auto& gn = (k & 1) ? ga : gb;    // next tap's destination
            if (k + 1 < K2) {                // issue tap k+1 BEFORE consuming k
                const int4 nbi = pidx[(k + 1) * 64 + spx];
                GATHER_ISSUE(gn, nbi);
            }
            const uint4 wu = pwts[k * 64 + spx];
            union { unsigned u; __half2 h2; } w0{wu.x}, w1{wu.y}, w2{wu.z}, w3{wu.w};
            short* dst = &smem[k & 1][spx * LDSS + cq];
#pragma unroll
            for (int h = 0; h < 2; ++h) {    // two 8-channel halves
                union U8 { short8 s; __half2 h2[4]; };
                U8 u00{gc[h * 4 + 0]}, u01{gc[h * 4 + 1]};
                U8 u10{gc[h * 4 + 2]}, u11{gc[h * 4 + 3]}, rr;
#pragma unroll
                for (int p = 0; p < 4; ++p) {
                    rr.h2[p] = __hfma2(u11.h2[p], w3.h2,
                               __hfma2(u10.h2[p], w2.h2,
                               __hfma2(u01.h2[p], w1.h2,
                               __hmul2(u00.h2[p], w0.h2))));
                }
                *(short8*)(dst + h * 8) = rr.s;
            }
            LDS_BARRIER();                   // tile k ready (lgkm drain only)
        }
    } else {
        // ================= CONSUMER: LDS -> MFMA (af prefetch) =============
        const int widx = wave - 4;           // 0..3
        const int lane = tid & 63;
        const int col  = lane & 15;
        const int q    = lane >> 4;
        const int pix  = widx * 16 + col;    // tile-local pixel
        const f16x8* wf = (const f16x8*)wfrag;

        f32x4 acc[4];
#pragma unroll
        for (int mt = 0; mt < 4; ++mt) acc[mt] = (f32x4)0.0f;

        f16x8 afa[8], afb[8];                // double-buffered A-fragments
#pragma unroll
        for (int i = 0; i < 8; ++i) afa[i] = wf[i * 64 + lane];   // tap 0

#pragma unroll
        for (int k = 0; k < K2; ++k) {
            auto& af  = (k & 1) ? afb : afa;
            auto& afn = (k & 1) ? afa : afb;
            LDS_BARRIER();                   // wait tile k
            if (k + 1 < K2) {                // prefetch tap k+1's A-fragments
#pragma unroll
                for (int i = 0; i < 8; ++i)
                    afn[i] = wf[((k + 1) * 8 + i) * 64 + lane];
            }
#pragma unroll
            for (int kk = 0; kk < 2; ++kk) {
                const f16x8 bfrag =
                    *(const f16x8*)(&smem[k & 1][pix * LDSS + kk * 32 + q * 8]);
#pragma unroll
                for (int mt = 0; mt < 4; ++mt)
                    acc[mt] = __builtin_amdgcn_mfma_f32_16x16x32_f16(
                        af[kk * 4 + mt], bfrag, acc[mt], 0, 0, 0);
            }
        }

        // ---- epilogue: D row=(q*4+r) -> o, col -> px ----
        const int wo = px0 + pix;
#pragma unroll
        for (int mt = 0; mt < 4; ++mt) {
#pragma unroll
            for (int r = 0; r < 4; ++r) {
                const int o = mt * 16 + q * 4 + r;
                out[(((size_t)b * COUT + o) * H + ho) * W + wo] =
                    acc[mt][r] + bias[o];
            }
        }
    }
}

// ---------- fallback (direct, no workspace) ----------
__global__ __launch_bounds__(256) void mdcn_direct_kernel(
    const float* __restrict__ x, const float* __restrict__ offset,
    const float* __restrict__ mask, const float* __restrict__ wsrc,
    const float* __restrict__ bias, float* __restrict__ out) {
    const int p  = blockIdx.x * blockDim.x + threadIdx.x;
    const int wo = p & (W - 1);
    const int ho = (p >> 7) & (H - 1);
    const int b  = p >> 14;
    float acc[COUT];
#pragma unroll
    for (int o = 0; o < COUT; ++o) acc[o] = bias[o];
    const float* xb = x + b * C * HW;
    for (int k = 0; k < K2; ++k) {
        const int ky = k / 3, kx = k % 3;
        const float dx = offset[((b * 2 * K2 + 2 * k    ) * H + ho) * W + wo];
        const float dy = offset[((b * 2 * K2 + 2 * k + 1) * H + ho) * W + wo];
        const float m  = mask  [((b * K2     + k        ) * H + ho) * W + wo];
        const float py = (float)(ho - 1 + ky) + dy;
        const float px = (float)(wo - 1 + kx) + dx;
        const float y0f = floorf(py), x0f = floorf(px);
        const float wy1 = py - y0f, wx1 = px - x0f;
        const float wy0 = 1.0f - wy1, wx0 = 1.0f - wx1;
        const int iy0 = (int)y0f, ix0 = (int)x0f;
        const int iy1 = iy0 + 1, ix1 = ix0 + 1;
        const bool vy0 = (iy0 >= 0) & (iy0 < H);
        const bool vy1 = (iy1 >= 0) & (iy1 < H);
        const bool vx0 = (ix0 >= 0) & (ix0 < W);
        const bool vx1 = (ix1 >= 0) & (ix1 < W);
        const float w00 = (vy0 & vx0) ? wy0 * wx0 * m : 0.0f;
        const float w01 = (vy0 & vx1) ? wy0 * wx1 * m : 0.0f;
        const float w10 = (vy1 & vx0) ? wy1 * wx0 * m : 0.0f;
        const float w11 = (vy1 & vx1) ? wy1 * wx1 * m : 0.0f;
        const int cy0 = min(max(iy0, 0), H - 1);
        const int cy1 = min(max(iy1, 0), H - 1);
        const int cx0 = min(max(ix0, 0), W - 1);
        const int cx1 = min(max(ix1, 0), W - 1);
        const int o00 = cy0 * W + cx0, o01 = cy0 * W + cx1;
        const int o10 = cy1 * W + cx0, o11 = cy1 * W + cx1;
        for (int c = 0; c < C; ++c) {
            const float* xp = xb + c * HW;
            const float val = w00 * xp[o00] + w01 * xp[o01] +
                              w10 * xp[o10] + w11 * xp[o11];
#pragma unroll
            for (int o = 0; o < COUT; ++o)
                acc[o] += wsrc[(o * C + c) * K2 + k] * val;
        }
    }
    float* op = out + ((size_t)b * COUT) * HW + ho * W + wo;
#pragma unroll
    for (int o = 0; o < COUT; ++o) op[o * HW] = acc[o];
}

extern "C" void kernel_launch(void* const* d_in, const int* in_sizes, int n_in,
                              void* d_out, int out_size, void* d_ws, size_t ws_size,
                              hipStream_t stream) {
    const float* x      = (const float*)d_in[0];
    const float* offset = (const float*)d_in[1];
    const float* mask   = (const float*)d_in[2];
    const float* weight = (const float*)d_in[3];
    const float* bias   = (const float*)d_in[4];
    float* out          = (float*)d_out;

    const size_t xt_bytes = (size_t)B * HW * C * sizeof(short);   // 16.78 MB
    const size_t wf_bytes = (size_t)COUT * C * K2 * sizeof(short);
    if (ws_size >= xt_bytes + wf_bytes) {
        short* xt    = (short*)d_ws;
        short* wfrag = (short*)((char*)d_ws + xt_bytes);
        transpose_x_kernel<<<B * (HW / 64), 256, 0, stream>>>(x, xt);
        pack_w_kernel<<<(COUT * C * K2 + 255) / 256, 256, 0, stream>>>(weight, wfrag);
        mdcn_pc_kernel<<<2 * B * H, 512, 0, stream>>>(xt, offset, mask, wfrag, bias, out);
    } else {
        mdcn_direct_kernel<<<(B * HW) / 256, 256, 0, stream>>>(
            x, offset, mask, weight, bias, out);
    }
}

// Round 7
// 139.095 us; speedup vs baseline: 1.0073x; 1.0073x over previous
//
#include <hip/hip_runtime.h>
#include <hip/hip_bf16.h>
#include <hip/hip_fp16.h>

// ModulatedDeformConv2d forward: f16 NHWC x, XCD-swizzled,
// producer/consumer wave-specialized fused sample+MFMA.
// R16 = R15 with the producer gather burst forced via inline-asm
// global_load_dwordx4 (opaque to the scheduler: cannot be serialized or
// register-chunked) + explicit counted s_waitcnt vmcnt(8): tap k+1's 8
// loads stay in flight while tap k is blended. R15 evidence: VGPR=36 =>
// compiler serialized the 8 gathers (8 x ~300cy L2 latency per tap on the
// critical path); dur identical to unpipelined R13.
// x[8,64,128,128] f32, offset[8,18,128,128], mask[8,9,128,128],
// weight[64,64,3,3], bias[64]; out[8,64,128,128] f32.

constexpr int B    = 8;
constexpr int C    = 64;
constexpr int H    = 128;
constexpr int W    = 128;
constexpr int COUT = 64;
constexpr int K2   = 9;
constexpr int HW   = H * W;
constexpr int TPX  = 64;   // pixels per tile

typedef __attribute__((ext_vector_type(8))) short    short8;
typedef __attribute__((ext_vector_type(8))) _Float16 f16x8;
typedef __attribute__((ext_vector_type(4))) float    f32x4;
typedef __attribute__((ext_vector_type(4))) int      i32x4;

// LDS tile row: 64 ch padded to 72 halves (144 B).
constexpr int LDSS = 72;

// Raw workgroup barrier: drain LDS ops only (no vmcnt(0) drain).
#define LDS_BARRIER() asm volatile("s_waitcnt lgkmcnt(0)\n\ts_barrier" ::: "memory")

// ---------- x: NCHW f32 -> NHWC f16 ----------
__global__ __launch_bounds__(256) void transpose_x_kernel(
    const float* __restrict__ x, short* __restrict__ xt) {
    __shared__ float tbuf[64][65];
    const int blk  = blockIdx.x;          // B * (HW/64) = 2048
    const int b    = blk >> 8;
    const int hwb  = (blk & 255) * 64;
    const int lane = threadIdx.x & 63;
    const int grp  = threadIdx.x >> 6;    // 0..3
    const float* xb = x + (size_t)b * C * HW;
#pragma unroll
    for (int r = 0; r < 16; ++r) {
        const int c = grp * 16 + r;
        tbuf[c][lane] = xb[c * HW + hwb + lane];   // coalesced along hw
    }
    __syncthreads();
    short* xo = xt + (size_t)b * HW * C;
#pragma unroll
    for (int r = 0; r < 16; ++r) {
        const int hw_l = grp * 16 + r;
        union { __half h; short s; } u;
        u.h = __float2half(tbuf[lane][hw_l]);
        xo[(size_t)(hwb + hw_l) * C + lane] = u.s;  // coalesced along c
    }
}

// ---------- weight[o][c][3][3] f32 -> A-fragment-ordered f16 ----------
// wfrag[(k*8 + kk*4 + mt)*64 + lane][j] = f16( w[m][c][k] )
//   m = mt*16 + (lane&15), q = lane>>4, c = kk*32 + q*8 + j
__global__ __launch_bounds__(256) void pack_w_kernel(
    const float* __restrict__ w, short* __restrict__ wfrag) {
    int id = blockIdx.x * blockDim.x + threadIdx.x;
    if (id >= COUT * C * K2) return;
    const int j    = id & 7;
    const int lane = (id >> 3) & 63;
    const int mt   = (id >> 9) & 3;
    const int kk   = (id >> 11) & 1;
    const int k    = id >> 12;
    const int m    = mt * 16 + (lane & 15);
    const int q    = lane >> 4;
    const int c    = kk * 32 + q * 8 + j;
    union { __half h; short s; } u;
    u.h = __float2half(w[(m * C + c) * K2 + k]);
    wfrag[id] = u.s;
}

// issue all 8 corner gathers of one tap into g[0..7] via opaque asm loads.
// [0..3] = corners (y0x0, y0x1, y1x0, y1x1) of 8-channel half 0,
// [4..7] = same corners, half 1 at +16 B (imm offset, no extra addr calc).
// "=&v" early-clobber: distinct dest quads, held live until the blend.
#define GATHER_ASM(g, bv) do {                                               \
    const char* a0_ = xb + (bv).x;                                           \
    const char* a1_ = xb + (bv).y;                                           \
    const char* a2_ = xb + (bv).z;                                           \
    const char* a3_ = xb + (bv).w;                                           \
    asm volatile("global_load_dwordx4 %0, %1, off"           : "=&v"(g[0]) : "v"(a0_)); \
    asm volatile("global_load_dwordx4 %0, %1, off"           : "=&v"(g[1]) : "v"(a1_)); \
    asm volatile("global_load_dwordx4 %0, %1, off"           : "=&v"(g[2]) : "v"(a2_)); \
    asm volatile("global_load_dwordx4 %0, %1, off"           : "=&v"(g[3]) : "v"(a3_)); \
    asm volatile("global_load_dwordx4 %0, %1, off offset:16" : "=&v"(g[4]) : "v"(a0_)); \
    asm volatile("global_load_dwordx4 %0, %1, off offset:16" : "=&v"(g[5]) : "v"(a1_)); \
    asm volatile("global_load_dwordx4 %0, %1, off offset:16" : "=&v"(g[6]) : "v"(a2_)); \
    asm volatile("global_load_dwordx4 %0, %1, off offset:16" : "=&v"(g[7]) : "v"(a3_)); \
} while (0)

// ---------- producer/consumer fused kernel ----------
// grid 2048: b = wg&7 (XCD round-robin -> per-XCD-L2-resident f16 x),
// t = wg>>3 -> (ho, 64-px half-row). 512 threads = 8 waves.
__global__ __launch_bounds__(512, 4) void mdcn_pc_kernel(
    const short* __restrict__ xt,      // [B][H][W][C] f16
    const float* __restrict__ offset,
    const float* __restrict__ mask,
    const short* __restrict__ wfrag,
    const float* __restrict__ bias,
    float* __restrict__ out) {

    __shared__ short smem[2][TPX * LDSS];    // 2 x 9216 B
    __shared__ int4  pidx[K2 * TPX];         // 9216 B: 4 corner byte-offsets
    __shared__ uint4 pwts[K2 * TPX];         // 9216 B: 4 blend wts as (h,h) half2

    const int wg   = blockIdx.x;
    const int b    = wg & 7;
    const int t    = wg >> 3;                // 0..255
    const int ho   = t >> 1;
    const int px0  = (t & 1) * TPX;

    const int tid  = threadIdx.x;
    const int wave = tid >> 6;

    // ---- precompute ALL taps' sampling params (one thread per (tap,px)) ----
    for (int f = tid; f < K2 * TPX; f += 512) {
        const int k = f >> 6;                // tap
        const int i = f & 63;                // tile-local pixel
        const int wo = px0 + i;
        const int ky = k / 3, kx = k % 3;
        const float dx = offset[(((size_t)b * 2 * K2 + 2 * k    ) * H + ho) * W + wo];
        const float dy = offset[(((size_t)b * 2 * K2 + 2 * k + 1) * H + ho) * W + wo];
        const float mm = mask  [(((size_t)b * K2     + k        ) * H + ho) * W + wo];
        const float py = (float)(ho - 1 + ky) + dy;
        const float px = (float)(wo - 1 + kx) + dx;
        const float y0f = floorf(py), x0f = floorf(px);
        const float wy1 = py - y0f,   wx1 = px - x0f;
        const float wy0 = 1.0f - wy1, wx0 = 1.0f - wx1;
        const int iy0 = (int)y0f, ix0 = (int)x0f;
        const int iy1 = iy0 + 1,  ix1 = ix0 + 1;
        const bool vy0 = (iy0 >= 0) & (iy0 < H);
        const bool vy1 = (iy1 >= 0) & (iy1 < H);
        const bool vx0 = (ix0 >= 0) & (ix0 < W);
        const bool vx1 = (ix1 >= 0) & (ix1 < W);
        const float w00 = (vy0 & vx0) ? wy0 * wx0 * mm : 0.0f;
        const float w01 = (vy0 & vx1) ? wy0 * wx1 * mm : 0.0f;
        const float w10 = (vy1 & vx0) ? wy1 * wx0 * mm : 0.0f;
        const float w11 = (vy1 & vx1) ? wy1 * wx1 * mm : 0.0f;
        union { __half2 h2; unsigned u; } c0, c1, c2, c3;
        c0.h2 = __floats2half2_rn(w00, w00);
        c1.h2 = __floats2half2_rn(w01, w01);
        c2.h2 = __floats2half2_rn(w10, w10);
        c3.h2 = __floats2half2_rn(w11, w11);
        uint4 wv;
        wv.x = c0.u; wv.y = c1.u; wv.z = c2.u; wv.w = c3.u;
        const int cy0 = min(max(iy0, 0), H - 1);
        const int cy1 = min(max(iy1, 0), H - 1);
        const int cx0 = min(max(ix0, 0), W - 1);
        const int cx1 = min(max(ix1, 0), W - 1);
        int4 bv;                              // byte offsets into xb
        bv.x = (cy0 * W + cx0) * (C * 2);
        bv.y = (cy0 * W + cx1) * (C * 2);
        bv.z = (cy1 * W + cx0) * (C * 2);
        bv.w = (cy1 * W + cx1) * (C * 2);
        pidx[f] = bv;
        pwts[f] = wv;
    }
    __syncthreads();                         // init barrier (full fence, once)

    if (wave < 4) {
        // ======== PRODUCER: asm gather burst, counted vmcnt pipeline ========
        const int spx = tid >> 2;            // 0..63 pixel in tile
        const int cq  = (tid & 3) * 16;      // 16-channel quarter
        const char* xb =
            (const char*)(xt + (size_t)b * HW * C) + cq * 2;

        i32x4 ga[8], gb[8];                  // double-buffered gather dests
        {
            const int4 bi0 = pidx[spx];      // tap 0 corner offsets
            GATHER_ASM(ga, bi0);             // tap 0 burst in flight
        }
#pragma unroll
        for (int k = 0; k < K2; ++k) {
            i32x4* gc = (k & 1) ? gb : ga;   // tap k's data (in flight)
            i32x4* gn = (k & 1) ? ga : gb;   // tap k+1's destination
            if (k + 1 < K2) {
                const int4 nbi = pidx[(k + 1) * 64 + spx];
                GATHER_ASM(gn, nbi);         // issue k+1 burst (8 newest)
                asm volatile("s_waitcnt vmcnt(8)" ::: "memory");  // drain tap k only
            } else {
                asm volatile("s_waitcnt vmcnt(0)" ::: "memory");  // last tap
            }
            __builtin_amdgcn_sched_barrier(0);   // rule #18: pin uses after wait

            const uint4 wu = pwts[k * 64 + spx];
            union { unsigned u; __half2 h2; } w0{wu.x}, w1{wu.y}, w2{wu.z}, w3{wu.w};
            short* dst = &smem[k & 1][spx * LDSS + cq];
#pragma unroll
            for (int h = 0; h < 2; ++h) {    // two 8-channel halves
                union U8 { i32x4 v; __half2 h2[4]; short8 s; };
                U8 u00{gc[h * 4 + 0]}, u01{gc[h * 4 + 1]};
                U8 u10{gc[h * 4 + 2]}, u11{gc[h * 4 + 3]}, rr;
#pragma unroll
                for (int p = 0; p < 4; ++p) {
                    rr.h2[p] = __hfma2(u11.h2[p], w3.h2,
                               __hfma2(u10.h2[p], w2.h2,
                               __hfma2(u01.h2[p], w1.h2,
                               __hmul2(u00.h2[p], w0.h2))));
                }
                *(short8*)(dst + h * 8) = rr.s;
            }
            LDS_BARRIER();                   // tile k ready (lgkm drain only)
        }
    } else {
        // ================= CONSUMER: LDS -> MFMA (af prefetch) =============
        const int widx = wave - 4;           // 0..3
        const int lane = tid & 63;
        const int col  = lane & 15;
        const int q    = lane >> 4;
        const int pix  = widx * 16 + col;    // tile-local pixel
        const f16x8* wf = (const f16x8*)wfrag;

        f32x4 acc[4];
#pragma unroll
        for (int mt = 0; mt < 4; ++mt) acc[mt] = (f32x4)0.0f;

        f16x8 afa[8], afb[8];                // double-buffered A-fragments
#pragma unroll
        for (int i = 0; i < 8; ++i) afa[i] = wf[i * 64 + lane];   // tap 0

#pragma unroll
        for (int k = 0; k < K2; ++k) {
            auto& af  = (k & 1) ? afb : afa;
            auto& afn = (k & 1) ? afa : afb;
            LDS_BARRIER();                   // wait tile k
            if (k + 1 < K2) {                // prefetch tap k+1's A-fragments
#pragma unroll
                for (int i = 0; i < 8; ++i)
                    afn[i] = wf[((k + 1) * 8 + i) * 64 + lane];
            }
#pragma unroll
            for (int kk = 0; kk < 2; ++kk) {
                const f16x8 bfrag =
                    *(const f16x8*)(&smem[k & 1][pix * LDSS + kk * 32 + q * 8]);
#pragma unroll
                for (int mt = 0; mt < 4; ++mt)
                    acc[mt] = __builtin_amdgcn_mfma_f32_16x16x32_f16(
                        af[kk * 4 + mt], bfrag, acc[mt], 0, 0, 0);
            }
        }

        // ---- epilogue: D row=(q*4+r) -> o, col -> px ----
        const int wo = px0 + pix;
#pragma unroll
        for (int mt = 0; mt < 4; ++mt) {
#pragma unroll
            for (int r = 0; r < 4; ++r) {
                const int o = mt * 16 + q * 4 + r;
                out[(((size_t)b * COUT + o) * H + ho) * W + wo] =
                    acc[mt][r] + bias[o];
            }
        }
    }
}

// ---------- fallback (direct, no workspace) ----------
__global__ __launch_bounds__(256) void mdcn_direct_kernel(
    const float* __restrict__ x, const float* __restrict__ offset,
    const float* __restrict__ mask, const float* __restrict__ wsrc,
    const float* __restrict__ bias, float* __restrict__ out) {
    const int p  = blockIdx.x * blockDim.x + threadIdx.x;
    const int wo = p & (W - 1);
    const int ho = (p >> 7) & (H - 1);
    const int b  = p >> 14;
    float acc[COUT];
#pragma unroll
    for (int o = 0; o < COUT; ++o) acc[o] = bias[o];
    const float* xb = x + b * C * HW;
    for (int k = 0; k < K2; ++k) {
        const int ky = k / 3, kx = k % 3;
        const float dx = offset[((b * 2 * K2 + 2 * k    ) * H + ho) * W + wo];
        const float dy = offset[((b * 2 * K2 + 2 * k + 1) * H + ho) * W + wo];
        const float m  = mask  [((b * K2     + k        ) * H + ho) * W + wo];
        const float py = (float)(ho - 1 + ky) + dy;
        const float px = (float)(wo - 1 + kx) + dx;
        const float y0f = floorf(py), x0f = floorf(px);
        const float wy1 = py - y0f, wx1 = px - x0f;
        const float wy0 = 1.0f - wy1, wx0 = 1.0f - wx1;
        const int iy0 = (int)y0f, ix0 = (int)x0f;
        const int iy1 = iy0 + 1, ix1 = ix0 + 1;
        const bool vy0 = (iy0 >= 0) & (iy0 < H);
        const bool vy1 = (iy1 >= 0) & (iy1 < H);
        const bool vx0 = (ix0 >= 0) & (ix0 < W);
        const bool vx1 = (ix1 >= 0) & (ix1 < W);
        const float w00 = (vy0 & vx0) ? wy0 * wx0 * m : 0.0f;
        const float w01 = (vy0 & vx1) ? wy0 * wx1 * m : 0.0f;
        const float w10 = (vy1 & vx0) ? wy1 * wx0 * m : 0.0f;
        const float w11 = (vy1 & vx1) ? wy1 * wx1 * m : 0.0f;
        const int cy0 = min(max(iy0, 0), H - 1);
        const int cy1 = min(max(iy1, 0), H - 1);
        const int cx0 = min(max(ix0, 0), W - 1);
        const int cx1 = min(max(ix1, 0), W - 1);
        const int o00 = cy0 * W + cx0, o01 = cy0 * W + cx1;
        const int o10 = cy1 * W + cx0, o11 = cy1 * W + cx1;
        for (int c = 0; c < C; ++c) {
            const float* xp = xb + c * HW;
            const float val = w00 * xp[o00] + w01 * xp[o01] +
                              w10 * xp[o10] + w11 * xp[o11];
#pragma unroll
            for (int o = 0; o < COUT; ++o)
                acc[o] += wsrc[(o * C + c) * K2 + k] * val;
        }
    }
    float* op = out + ((size_t)b * COUT) * HW + ho * W + wo;
#pragma unroll
    for (int o = 0; o < COUT; ++o) op[o * HW] = acc[o];
}

extern "C" void kernel_launch(void* const* d_in, const int* in_sizes, int n_in,
                              void* d_out, int out_size, void* d_ws, size_t ws_size,
                              hipStream_t stream) {
    const float* x      = (const float*)d_in[0];
    const float* offset = (const float*)d_in[1];
    const float* mask   = (const float*)d_in[2];
    const float* weight = (const float*)d_in[3];
    const float* bias   = (const float*)d_in[4];
    float* out          = (float*)d_out;

    const size_t xt_bytes = (size_t)B * HW * C * sizeof(short);   // 16.78 MB
    const size_t wf_bytes = (size_t)COUT * C * K2 * sizeof(short);
    if (ws_size >= xt_bytes + wf_bytes) {
        short* xt    = (short*)d_ws;
        short* wfrag = (short*)((char*)d_ws + xt_bytes);
        transpose_x_kernel<<<B * (HW / 64), 256, 0, stream>>>(x, xt);
        pack_w_kernel<<<(COUT * C * K2 + 255) / 256, 256, 0, stream>>>(weight, wfrag);
        mdcn_pc_kernel<<<2 * B * H, 512, 0, stream>>>(xt, offset, mask, wfrag, bias, out);
    } else {
        mdcn_direct_kernel<<<(B * HW) / 256, 256, 0, stream>>>(
            x, offset, mask, weight, bias, out);
    }
}

// Round 8
// 129.805 us; speedup vs baseline: 1.0794x; 1.0716x over previous
//
#include <hip/hip_runtime.h>
#include <hip/hip_bf16.h>
#include <hip/hip_fp16.h>

// ModulatedDeformConv2d forward: f16 NHWC x, XCD-swizzled,
// producer/consumer wave-specialized fused sample+MFMA.
// R17: consumer waves partition OUTPUT CHANNELS (wave w owns outputs
// [16w,16w+16) for all 64 pixels) instead of pixels. Each consumer wave
// now loads only its own 2 A-fragments per tap (was 8, with all 4 waves
// reading identical data): 4x fewer scattered VMEM instructions on the
// CU's address pipe, which R13/R15/R16's 3-way 50us invariance identified
// as the bound. B-fragments read from LDS (8 ds_read_b128/wave/tap).
// Producer = plain R13 form (scheduling is moot under throughput bound).
// x[8,64,128,128] f32, offset[8,18,128,128], mask[8,9,128,128],
// weight[64,64,3,3], bias[64]; out[8,64,128,128] f32.

constexpr int B    = 8;
constexpr int C    = 64;
constexpr int H    = 128;
constexpr int W    = 128;
constexpr int COUT = 64;
constexpr int K2   = 9;
constexpr int HW   = H * W;
constexpr int TPX  = 64;   // pixels per tile

typedef __attribute__((ext_vector_type(8))) short    short8;
typedef __attribute__((ext_vector_type(8))) _Float16 f16x8;
typedef __attribute__((ext_vector_type(4))) float    f32x4;

// LDS tile row: 64 ch padded to 72 halves (144 B).
constexpr int LDSS = 72;

// Raw workgroup barrier: drain LDS ops only (no vmcnt(0) drain).
#define LDS_BARRIER() asm volatile("s_waitcnt lgkmcnt(0)\n\ts_barrier" ::: "memory")

// ---------- x: NCHW f32 -> NHWC f16 ----------
__global__ __launch_bounds__(256) void transpose_x_kernel(
    const float* __restrict__ x, short* __restrict__ xt) {
    __shared__ float tbuf[64][65];
    const int blk  = blockIdx.x;          // B * (HW/64) = 2048
    const int b    = blk >> 8;
    const int hwb  = (blk & 255) * 64;
    const int lane = threadIdx.x & 63;
    const int grp  = threadIdx.x >> 6;    // 0..3
    const float* xb = x + (size_t)b * C * HW;
#pragma unroll
    for (int r = 0; r < 16; ++r) {
        const int c = grp * 16 + r;
        tbuf[c][lane] = xb[c * HW + hwb + lane];   // coalesced along hw
    }
    __syncthreads();
    short* xo = xt + (size_t)b * HW * C;
#pragma unroll
    for (int r = 0; r < 16; ++r) {
        const int hw_l = grp * 16 + r;
        union { __half h; short s; } u;
        u.h = __float2half(tbuf[lane][hw_l]);
        xo[(size_t)(hwb + hw_l) * C + lane] = u.s;  // coalesced along c
    }
}

// ---------- weight[o][c][3][3] f32 -> A-fragment-ordered f16 ----------
// wfrag[(k*8 + kk*4 + mt)*64 + lane][j] = f16( w[m][c][k] )
//   m = mt*16 + (lane&15), q = lane>>4, c = kk*32 + q*8 + j
__global__ __launch_bounds__(256) void pack_w_kernel(
    const float* __restrict__ w, short* __restrict__ wfrag) {
    int id = blockIdx.x * blockDim.x + threadIdx.x;
    if (id >= COUT * C * K2) return;
    const int j    = id & 7;
    const int lane = (id >> 3) & 63;
    const int mt   = (id >> 9) & 3;
    const int kk   = (id >> 11) & 1;
    const int k    = id >> 12;
    const int m    = mt * 16 + (lane & 15);
    const int q    = lane >> 4;
    const int c    = kk * 32 + q * 8 + j;
    union { __half h; short s; } u;
    u.h = __float2half(w[(m * C + c) * K2 + k]);
    wfrag[id] = u.s;
}

// ---------- producer/consumer fused kernel ----------
// grid 2048: b = wg&7 (XCD round-robin -> per-XCD-L2-resident f16 x),
// t = wg>>3 -> (ho, 64-px half-row). 512 threads = 8 waves.
__global__ __launch_bounds__(512, 4) void mdcn_pc_kernel(
    const short* __restrict__ xt,      // [B][H][W][C] f16
    const float* __restrict__ offset,
    const float* __restrict__ mask,
    const short* __restrict__ wfrag,
    const float* __restrict__ bias,
    float* __restrict__ out) {

    __shared__ short smem[2][TPX * LDSS];    // 2 x 9216 B
    __shared__ int4  pidx[K2 * TPX];         // 9216 B: 4 corner byte-offsets
    __shared__ uint4 pwts[K2 * TPX];         // 9216 B: 4 blend wts as (h,h) half2

    const int wg   = blockIdx.x;
    const int b    = wg & 7;
    const int t    = wg >> 3;                // 0..255
    const int ho   = t >> 1;
    const int px0  = (t & 1) * TPX;

    const int tid  = threadIdx.x;
    const int wave = tid >> 6;

    // ---- precompute ALL taps' sampling params (one thread per (tap,px)) ----
    for (int f = tid; f < K2 * TPX; f += 512) {
        const int k = f >> 6;                // tap
        const int i = f & 63;                // tile-local pixel
        const int wo = px0 + i;
        const int ky = k / 3, kx = k % 3;
        const float dx = offset[(((size_t)b * 2 * K2 + 2 * k    ) * H + ho) * W + wo];
        const float dy = offset[(((size_t)b * 2 * K2 + 2 * k + 1) * H + ho) * W + wo];
        const float mm = mask  [(((size_t)b * K2     + k        ) * H + ho) * W + wo];
        const float py = (float)(ho - 1 + ky) + dy;
        const float px = (float)(wo - 1 + kx) + dx;
        const float y0f = floorf(py), x0f = floorf(px);
        const float wy1 = py - y0f,   wx1 = px - x0f;
        const float wy0 = 1.0f - wy1, wx0 = 1.0f - wx1;
        const int iy0 = (int)y0f, ix0 = (int)x0f;
        const int iy1 = iy0 + 1,  ix1 = ix0 + 1;
        const bool vy0 = (iy0 >= 0) & (iy0 < H);
        const bool vy1 = (iy1 >= 0) & (iy1 < H);
        const bool vx0 = (ix0 >= 0) & (ix0 < W);
        const bool vx1 = (ix1 >= 0) & (ix1 < W);
        const float w00 = (vy0 & vx0) ? wy0 * wx0 * mm : 0.0f;
        const float w01 = (vy0 & vx1) ? wy0 * wx1 * mm : 0.0f;
        const float w10 = (vy1 & vx0) ? wy1 * wx0 * mm : 0.0f;
        const float w11 = (vy1 & vx1) ? wy1 * wx1 * mm : 0.0f;
        union { __half2 h2; unsigned u; } c0, c1, c2, c3;
        c0.h2 = __floats2half2_rn(w00, w00);
        c1.h2 = __floats2half2_rn(w01, w01);
        c2.h2 = __floats2half2_rn(w10, w10);
        c3.h2 = __floats2half2_rn(w11, w11);
        uint4 wv;
        wv.x = c0.u; wv.y = c1.u; wv.z = c2.u; wv.w = c3.u;
        const int cy0 = min(max(iy0, 0), H - 1);
        const int cy1 = min(max(iy1, 0), H - 1);
        const int cx0 = min(max(ix0, 0), W - 1);
        const int cx1 = min(max(ix1, 0), W - 1);
        int4 bv;                              // byte offsets into xb
        bv.x = (cy0 * W + cx0) * (C * 2);
        bv.y = (cy0 * W + cx1) * (C * 2);
        bv.z = (cy1 * W + cx0) * (C * 2);
        bv.w = (cy1 * W + cx1) * (C * 2);
        pidx[f] = bv;
        pwts[f] = wv;
    }
    __syncthreads();                         // init barrier (full fence, once)

    if (wave < 4) {
        // ================= PRODUCER: sample -> LDS =================
        const int spx = tid >> 2;            // 0..63 pixel in tile
        const int cq  = (tid & 3) * 16;      // 16-channel quarter
        const char* xb =
            (const char*)(xt + (size_t)b * HW * C) + cq * 2;

        for (int k = 0; k < K2; ++k) {
            const int4  bi = pidx[k * 64 + spx];    // ds_read_b128 (4-px bcast)
            const uint4 wu = pwts[k * 64 + spx];
            union { unsigned u; __half2 h2; } w0{wu.x}, w1{wu.y}, w2{wu.z}, w3{wu.w};
            const short* s00 = (const short*)(xb + bi.x);
            const short* s01 = (const short*)(xb + bi.y);
            const short* s10 = (const short*)(xb + bi.z);
            const short* s11 = (const short*)(xb + bi.w);

            short* dst = &smem[k & 1][spx * LDSS + cq];
#pragma unroll
            for (int h = 0; h < 2; ++h) {    // two 8-channel halves
                union U8 { short8 s; __half2 h2[4]; };
                const U8 g00{*(const short8*)(s00 + h * 8)};
                const U8 g01{*(const short8*)(s01 + h * 8)};
                const U8 g10{*(const short8*)(s10 + h * 8)};
                const U8 g11{*(const short8*)(s11 + h * 8)};
                U8 rr;
#pragma unroll
                for (int p = 0; p < 4; ++p) {
                    rr.h2[p] = __hfma2(g11.h2[p], w3.h2,
                               __hfma2(g10.h2[p], w2.h2,
                               __hfma2(g01.h2[p], w1.h2,
                               __hmul2(g00.h2[p], w0.h2))));
                }
                *(short8*)(dst + h * 8) = rr.s;
            }
            LDS_BARRIER();                   // tile k ready (lgkm drain only)
        }
    } else {
        // ====== CONSUMER: output-channel-partitioned LDS -> MFMA ======
        // wave w owns outputs [16w, 16w+16) for ALL 64 pixels.
        const int w    = wave - 4;           // 0..3 output quarter
        const int lane = tid & 63;
        const int col  = lane & 15;
        const int q    = lane >> 4;
        const f16x8* wf = (const f16x8*)wfrag;

        f32x4 acc[4];
#pragma unroll
        for (int nt = 0; nt < 4; ++nt) acc[nt] = (f32x4)0.0f;

        f16x8 afa[2], afb[2];                // double-buffered A-fragments
#pragma unroll
        for (int kk = 0; kk < 2; ++kk)       // tap 0: only this wave's 2 frags
            afa[kk] = wf[(kk * 4 + w) * 64 + lane];

#pragma unroll
        for (int k = 0; k < K2; ++k) {
            auto& af  = (k & 1) ? afb : afa;
            auto& afn = (k & 1) ? afa : afb;
            LDS_BARRIER();                   // wait tile k
            if (k + 1 < K2) {                // prefetch tap k+1's 2 A-frags
#pragma unroll
                for (int kk = 0; kk < 2; ++kk)
                    afn[kk] = wf[((k + 1) * 8 + kk * 4 + w) * 64 + lane];
            }
#pragma unroll
            for (int kk = 0; kk < 2; ++kk) {
#pragma unroll
                for (int nt = 0; nt < 4; ++nt) {
                    const f16x8 bfrag = *(const f16x8*)(
                        &smem[k & 1][(nt * 16 + col) * LDSS + kk * 32 + q * 8]);
                    acc[nt] = __builtin_amdgcn_mfma_f32_16x16x32_f16(
                        af[kk], bfrag, acc[nt], 0, 0, 0);
                }
            }
        }

        // ---- epilogue: D row=(q*4+r) -> o = w*16+q*4+r, col -> px ----
#pragma unroll
        for (int nt = 0; nt < 4; ++nt) {
            const int wo = px0 + nt * 16 + col;
#pragma unroll
            for (int r = 0; r < 4; ++r) {
                const int o = w * 16 + q * 4 + r;
                out[(((size_t)b * COUT + o) * H + ho) * W + wo] =
                    acc[nt][r] + bias[o];
            }
        }
    }
}

// ---------- fallback (direct, no workspace) ----------
__global__ __launch_bounds__(256) void mdcn_direct_kernel(
    const float* __restrict__ x, const float* __restrict__ offset,
    const float* __restrict__ mask, const float* __restrict__ wsrc,
    const float* __restrict__ bias, float* __restrict__ out) {
    const int p  = blockIdx.x * blockDim.x + threadIdx.x;
    const int wo = p & (W - 1);
    const int ho = (p >> 7) & (H - 1);
    const int b  = p >> 14;
    float acc[COUT];
#pragma unroll
    for (int o = 0; o < COUT; ++o) acc[o] = bias[o];
    const float* xb = x + b * C * HW;
    for (int k = 0; k < K2; ++k) {
        const int ky = k / 3, kx = k % 3;
        const float dx = offset[((b * 2 * K2 + 2 * k    ) * H + ho) * W + wo];
        const float dy = offset[((b * 2 * K2 + 2 * k + 1) * H + ho) * W + wo];
        const float m  = mask  [((b * K2     + k        ) * H + ho) * W + wo];
        const float py = (float)(ho - 1 + ky) + dy;
        const float px = (float)(wo - 1 + kx) + dx;
        const float y0f = floorf(py), x0f = floorf(px);
        const float wy1 = py - y0f, wx1 = px - x0f;
        const float wy0 = 1.0f - wy1, wx0 = 1.0f - wx1;
        const int iy0 = (int)y0f, ix0 = (int)x0f;
        const int iy1 = iy0 + 1, ix1 = ix0 + 1;
        const bool vy0 = (iy0 >= 0) & (iy0 < H);
        const bool vy1 = (iy1 >= 0) & (iy1 < H);
        const bool vx0 = (ix0 >= 0) & (ix0 < W);
        const bool vx1 = (ix1 >= 0) & (ix1 < W);
        const float w00 = (vy0 & vx0) ? wy0 * wx0 * m : 0.0f;
        const float w01 = (vy0 & vx1) ? wy0 * wx1 * m : 0.0f;
        const float w10 = (vy1 & vx0) ? wy1 * wx0 * m : 0.0f;
        const float w11 = (vy1 & vx1) ? wy1 * wx1 * m : 0.0f;
        const int cy0 = min(max(iy0, 0), H - 1);
        const int cy1 = min(max(iy1, 0), H - 1);
        const int cx0 = min(max(ix0, 0), W - 1);
        const int cx1 = min(max(ix1, 0), W - 1);
        const int o00 = cy0 * W + cx0, o01 = cy0 * W + cx1;
        const int o10 = cy1 * W + cx0, o11 = cy1 * W + cx1;
        for (int c = 0; c < C; ++c) {
            const float* xp = xb + c * HW;
            const float val = w00 * xp[o00] + w01 * xp[o01] +
                              w10 * xp[o10] + w11 * xp[o11];
#pragma unroll
            for (int o = 0; o < COUT; ++o)
                acc[o] += wsrc[(o * C + c) * K2 + k] * val;
        }
    }
    float* op = out + ((size_t)b * COUT) * HW + ho * W + wo;
#pragma unroll
    for (int o = 0; o < COUT; ++o) op[o * HW] = acc[o];
}

extern "C" void kernel_launch(void* const* d_in, const int* in_sizes, int n_in,
                              void* d_out, int out_size, void* d_ws, size_t ws_size,
                              hipStream_t stream) {
    const float* x      = (const float*)d_in[0];
    const float* offset = (const float*)d_in[1];
    const float* mask   = (const float*)d_in[2];
    const float* weight = (const float*)d_in[3];
    const float* bias   = (const float*)d_in[4];
    float* out          = (float*)d_out;

    const size_t xt_bytes = (size_t)B * HW * C * sizeof(short);   // 16.78 MB
    const size_t wf_bytes = (size_t)COUT * C * K2 * sizeof(short);
    if (ws_size >= xt_bytes + wf_bytes) {
        short* xt    = (short*)d_ws;
        short* wfrag = (short*)((char*)d_ws + xt_bytes);
        transpose_x_kernel<<<B * (HW / 64), 256, 0, stream>>>(x, xt);
        pack_w_kernel<<<(COUT * C * K2 + 255) / 256, 256, 0, stream>>>(weight, wfrag);
        mdcn_pc_kernel<<<2 * B * H, 512, 0, stream>>>(xt, offset, mask, wfrag, bias, out);
    } else {
        mdcn_direct_kernel<<<(B * HW) / 256, 256, 0, stream>>>(
            x, offset, mask, weight, bias, out);
    }
}